// Round 12
// baseline (927.889 us; speedup 1.0000x reference)
//
#include <hip/hip_runtime.h>
#include <math.h>

constexpr int Bc = 16;
constexpr int Nc = 8192;
constexpr int Sc = 512;
constexpr int Kc = 32;
constexpr int Pc = Bc * Sc * Kc; // 262144

// DPP-assisted wave64 max stage (ctrl is a compile-time constant)
template <int CTRL>
__device__ __forceinline__ float dpp_max_stage(float x) {
  int p = __builtin_amdgcn_update_dpp(0, __float_as_int(x), CTRL, 0xf, 0xf, true);
  return fmaxf(x, __int_as_float(p));
}

// ---------------------------------------------------------------------------
// FPS: one block (512 thr = 8 waves, 2 waves/SIMD) per batch, 16 pts/thread.
// vs r11 (256 thr): same total VALU issue, but 2 waves/SIMD co-schedule so
// dependent-chain stalls (argmax tracking, LDS latency, reduction tail) are
// filled by the sibling wave; per-wave serial chains halve (16 steps).
// Points mirrored in LDS; no VMEM in the loop. Scalar no-FMA distance
// (bit-exact), strict-> argmax (first-occurrence), DPP wave max + ballot
// index, 8 u64 LDS slots (double-buffered), ONE barrier, 8-read local
// compare, post-barrier lx[sfar] broadcast fetch (r10 lesson: keep it here).
// ---------------------------------------------------------------------------
__global__ __launch_bounds__(512, 1)
void fps_kernel(const float* __restrict__ data,
                float* __restrict__ cent_out,
                float* __restrict__ cent_ws) {
  const int b = blockIdx.x;
  const int t = threadIdx.x;
  const int lane = t & 63, w = t >> 6;   // w in 0..7

  __shared__ float lx[Nc], ly[Nc], lz[Nc];          // 96 KB point mirror
  __shared__ unsigned long long red_k[2][8];
  __shared__ int idx_hist[Sc];

  const float* db = data + (size_t)b * Nc * 3;

  float px[16], py[16], pz[16], dist[16];
#pragma unroll
  for (int j = 0; j < 16; ++j) {
    int p = t + 512 * j;
    px[j] = db[p * 3 + 0];
    py[j] = db[p * 3 + 1];
    pz[j] = db[p * 3 + 2];
    dist[j] = 1e10f;
    lx[p] = px[j]; ly[p] = py[j]; lz[p] = pz[j];
  }
  __syncthreads();

  int far = 0;
  for (int it = 0; it < Sc; ++it) {
    const int sfar = __builtin_amdgcn_readfirstlane(far);
    if (t == 0) idx_hist[it] = sfar;
    const float cx = lx[sfar];
    const float cy = ly[sfar];
    const float cz = lz[sfar];

    float best = -1.0f; int bj = 0;
#pragma unroll
    for (int j = 0; j < 16; ++j) {
      float dx = __fsub_rn(px[j], cx);
      float dy = __fsub_rn(py[j], cy);
      float dz = __fsub_rn(pz[j], cz);
      float d = __fadd_rn(__fadd_rn(__fmul_rn(dx, dx), __fmul_rn(dy, dy)),
                          __fmul_rn(dz, dz));
      float nd = fminf(dist[j], d);
      dist[j] = nd;
      if (nd > best) { best = nd; bj = j; }  // strict >: first index in lane
    }
    const int bidx = t + 512 * bj;

    // wave max: DPP within row16, shfl across rows
    float wmax = best;
    wmax = dpp_max_stage<0xB1>(wmax);   // quad_perm [1,0,3,2]
    wmax = dpp_max_stage<0x4E>(wmax);   // quad_perm [2,3,0,1]
    wmax = dpp_max_stage<0x141>(wmax);  // row_half_mirror
    wmax = dpp_max_stage<0x140>(wmax);  // row_mirror
    wmax = fmaxf(wmax, __shfl_xor(wmax, 16));
    wmax = fmaxf(wmax, __shfl_xor(wmax, 32));

    // index of first-occurrence achiever
    unsigned long long m = __ballot(best == wmax);
    int idx;
    if (__popcll(m) == 1) {
      idx = __shfl(bidx, (int)__ffsll((long long)m) - 1);
    } else {  // rare exact tie across lanes -> min point index
      int cand = (best == wmax) ? bidx : 0x7fffffff;
#pragma unroll
      for (int off = 32; off; off >>= 1) cand = min(cand, __shfl_xor(cand, off));
      idx = cand;
    }

    unsigned long long key =
        ((unsigned long long)__float_as_uint(wmax) << 32) |
        (unsigned long long)(0xFFFFFFFFu - (unsigned)idx);
    const int par = it & 1;
    if (lane == 0) red_k[par][w] = key;
    __syncthreads();                 // the only barrier; lgkm drain only

    unsigned long long k0 = red_k[par][0];
    unsigned long long k1 = red_k[par][1];
    unsigned long long k2 = red_k[par][2];
    unsigned long long k3 = red_k[par][3];
    unsigned long long k4 = red_k[par][4];
    unsigned long long k5 = red_k[par][5];
    unsigned long long k6 = red_k[par][6];
    unsigned long long k7 = red_k[par][7];
    unsigned long long ka = (k0 > k1) ? k0 : k1;
    unsigned long long kb = (k2 > k3) ? k2 : k3;
    unsigned long long kc = (k4 > k5) ? k4 : k5;
    unsigned long long kd = (k6 > k7) ? k6 : k7;
    unsigned long long ke = (ka > kb) ? ka : kb;
    unsigned long long kf = (kc > kd) ? kc : kd;
    unsigned long long kk = (ke > kf) ? ke : kf;
    far = (int)(0xFFFFFFFFu - (unsigned)(kk & 0xFFFFFFFFull));
  }

  __syncthreads();
  for (int s = t; s < Sc; s += 512) {
    int id = idx_hist[s];
    float vx = lx[id], vy = ly[id], vz = lz[id];
    size_t o = ((size_t)b * Sc + s) * 3;
    cent_out[o + 0] = vx; cent_out[o + 1] = vy; cent_out[o + 2] = vz;
    cent_ws[o + 0]  = vx; cent_ws[o + 1]  = vy; cent_ws[o + 2]  = vz;
  }
}

__global__ __launch_bounds__(256)
void ball_kernel(const float* __restrict__ data,
                 const float* __restrict__ feat,
                 const float* __restrict__ cent_ws,
                 float* __restrict__ x0) {
  const int w = threadIdx.x >> 6, lane = threadIdx.x & 63;
  const int q = blockIdx.x * 4 + w;
  const int b = q >> 9;
  const float* db = data + (size_t)b * Nc * 3;
  const float* fb = feat + (size_t)b * Nc * 3;

  const float qx = cent_ws[q * 3 + 0];
  const float qy = cent_ws[q * 3 + 1];
  const float qz = cent_ws[q * 3 + 2];
  const float q2 = __fadd_rn(__fadd_rn(__fmul_rn(qx, qx), __fmul_rn(qy, qy)),
                             __fmul_rn(qz, qz));

  __shared__ int nbr[4][Kc];
  int have = 0;
  for (int base = 0; base < Nc; base += 64) {
    int i = base + lane;
    float px = db[i * 3 + 0], py = db[i * 3 + 1], pz = db[i * 3 + 2];
    float p2 = __fadd_rn(__fadd_rn(__fmul_rn(px, px), __fmul_rn(py, py)),
                         __fmul_rn(pz, pz));
    float dt = fmaf(qz, pz, fmaf(qy, py, __fmul_rn(qx, px)));
    float d = __fadd_rn(__fadd_rn(__fmul_rn(-2.0f, dt), q2), p2);
    bool ok = d <= 0.16f;
    unsigned long long mask = __ballot(ok);
    if (mask) {
      int pos = have + __popcll(mask & ((1ull << lane) - 1ull));
      if (ok && pos < Kc) nbr[w][pos] = i;
      have += __popcll(mask);
      if (have >= Kc) break;
    }
  }
  if (have > Kc) have = Kc;
  __syncthreads();

  if (lane < Kc) {
    int k = lane;
    int j = nbr[w][k < have ? k : 0];
    float sx = __fsub_rn(db[j * 3 + 0], qx);
    float sy = __fsub_rn(db[j * 3 + 1], qy);
    float sz = __fsub_rn(db[j * 3 + 2], qz);
    float fx = fb[j * 3 + 0], fy = fb[j * 3 + 1], fz = fb[j * 3 + 2];
    size_t pidx = (size_t)q * Kc + k;
    x0[(size_t)0 * Pc + pidx] = sx;
    x0[(size_t)1 * Pc + pidx] = sy;
    x0[(size_t)2 * Pc + pidx] = sz;
    x0[(size_t)3 * Pc + pidx] = fx;
    x0[(size_t)4 * Pc + pidx] = fy;
    x0[(size_t)5 * Pc + pidx] = fz;
  }
}

__global__ __launch_bounds__(256)
void pass_a(const float* __restrict__ x0, const float* __restrict__ w0,
            const float* __restrict__ b0, float* __restrict__ part0) {
  const int lane = threadIdx.x & 63, w = threadIdx.x >> 6;
  const int slice = blockIdx.x * 4 + w;
  const int o = lane;
  float W[6];
#pragma unroll
  for (int c = 0; c < 6; ++c) W[c] = w0[o * 6 + c];
  const float bias = b0[o];
  float sum = 0.f, sq = 0.f;
  const int pps = Pc / 4096;   // 64
  const int p0 = slice * pps;
  for (int j = 0; j < pps; ++j) {
    int p = p0 + j;
    float y = bias;
#pragma unroll
    for (int c = 0; c < 6; ++c) y = fmaf(x0[(size_t)c * Pc + p], W[c], y);
    sum += y;
    sq = fmaf(y, y, sq);
  }
  __shared__ float bsum[64], bsq[64];
  if (threadIdx.x < 64) { bsum[threadIdx.x] = 0.f; bsq[threadIdx.x] = 0.f; }
  __syncthreads();
  atomicAdd(&bsum[o], sum);
  atomicAdd(&bsq[o], sq);
  __syncthreads();
  if (threadIdx.x < 64)       part0[blockIdx.x * 128 + threadIdx.x] = bsum[threadIdx.x];
  else if (threadIdx.x < 128) part0[blockIdx.x * 128 + threadIdx.x] = bsq[threadIdx.x - 64];
}

// One block per channel; 256-thread fixed-order tree (deterministic, double).
__global__ __launch_bounds__(256)
void reduce_k(const float* __restrict__ part, int nblk, int nch,
              const float* __restrict__ g, const float* __restrict__ be,
              float* __restrict__ AB) {
  const int o = blockIdx.x;
  const int t = threadIdx.x;
  double sum = 0.0, sq = 0.0;
  for (int i = t; i < nblk; i += 256) {
    sum += (double)part[(size_t)i * (2 * nch) + o];
    sq  += (double)part[(size_t)i * (2 * nch) + nch + o];
  }
  __shared__ double ls[256], lq[256];
  ls[t] = sum; lq[t] = sq;
  __syncthreads();
  for (int s = 128; s > 0; s >>= 1) {
    if (t < s) { ls[t] += ls[t + s]; lq[t] += lq[t + s]; }
    __syncthreads();
  }
  if (t == 0) {
    double m = ls[0] / (double)Pc;
    double v = lq[0] / (double)Pc - m * m;
    double A = (double)g[o] / sqrt(v + 1e-5);
    AB[o] = (float)A;
    AB[nch + o] = (float)((double)be[o] - m * A);
  }
}

// Stats: 2-level lane shuffle (groups of 4) + padded LDS slab, block epilogue.
__global__ __launch_bounds__(256)
void pass_b(const float* __restrict__ x0, const float* __restrict__ w0,
            const float* __restrict__ b0, const float* __restrict__ AB0,
            const float* __restrict__ w1, const float* __restrict__ b1,
            float* __restrict__ y1, float* __restrict__ part1) {
  const int p = blockIdx.x * 256 + threadIdx.x;
  const int lane = threadIdx.x & 63, w = threadIdx.x >> 6;

  float xin[6];
#pragma unroll
  for (int c = 0; c < 6; ++c) xin[c] = x0[(size_t)c * Pc + p];

  float x1[64];
#pragma unroll
  for (int o = 0; o < 64; ++o) {
    float y = b0[o];
#pragma unroll
    for (int c = 0; c < 6; ++c) y = fmaf(xin[c], w0[o * 6 + c], y);
    x1[o] = fmaxf(fmaf(y, AB0[o], AB0[64 + o]), 0.f);
  }

  __shared__ float ssum[4][64][17], ssq[4][64][17];  // padded: stride 17

  for (int o = 0; o < 64; ++o) {
    float a0 = b1[o], a1 = 0.f, a2 = 0.f, a3 = 0.f;
#pragma unroll
    for (int c = 0; c < 64; c += 4) {
      a0 = fmaf(x1[c + 0], w1[o * 64 + c + 0], a0);
      a1 = fmaf(x1[c + 1], w1[o * 64 + c + 1], a1);
      a2 = fmaf(x1[c + 2], w1[o * 64 + c + 2], a2);
      a3 = fmaf(x1[c + 3], w1[o * 64 + c + 3], a3);
    }
    float acc = (a0 + a1) + (a2 + a3);
    y1[(size_t)o * Pc + p] = acc;

    float sv = acc + __shfl_xor(acc, 1);
    sv += __shfl_xor(sv, 2);
    float q = acc * acc;
    float qv = q + __shfl_xor(q, 1);
    qv += __shfl_xor(qv, 2);
    if ((lane & 3) == 0) {
      ssum[w][o][lane >> 2] = sv;
      ssq[w][o][lane >> 2] = qv;
    }
  }
  __syncthreads();
  if (threadIdx.x < 128) {
    const int o = threadIdx.x & 63;
    const bool isq = threadIdx.x >= 64;
    float s = 0.f;
#pragma unroll
    for (int ww = 0; ww < 4; ++ww)
      for (int k = 0; k < 16; ++k)
        s += isq ? ssq[ww][o][k] : ssum[ww][o][k];
    part1[blockIdx.x * 128 + threadIdx.x] = s;
  }
}

// Stats: 3-level lane shuffle (groups of 8) + padded LDS slab, block epilogue.
__global__ __launch_bounds__(256)
void pass_c(const float* __restrict__ y1, const float* __restrict__ AB1,
            const float* __restrict__ w2, const float* __restrict__ b2,
            float* __restrict__ maxy2, float* __restrict__ part2) {
  const int p = blockIdx.x * 256 + threadIdx.x;
  const int lane = threadIdx.x & 63, w = threadIdx.x >> 6;
  const int grp = p >> 5;

  float x2[64];
#pragma unroll
  for (int c = 0; c < 64; ++c) {
    float v = y1[(size_t)c * Pc + p];
    x2[c] = fmaxf(fmaf(v, AB1[c], AB1[64 + c]), 0.f);
  }

  __shared__ float ssum[4][128][9], ssq[4][128][9];  // padded: stride 9

  for (int o = 0; o < 128; ++o) {
    float a0 = b2[o], a1 = 0.f, a2 = 0.f, a3 = 0.f;
#pragma unroll
    for (int c = 0; c < 64; c += 4) {
      a0 = fmaf(x2[c + 0], w2[o * 64 + c + 0], a0);
      a1 = fmaf(x2[c + 1], w2[o * 64 + c + 1], a1);
      a2 = fmaf(x2[c + 2], w2[o * 64 + c + 2], a2);
      a3 = fmaf(x2[c + 3], w2[o * 64 + c + 3], a3);
    }
    float acc = (a0 + a1) + (a2 + a3);

    float mx = acc;
#pragma unroll
    for (int off = 16; off > 0; off >>= 1) mx = fmaxf(mx, __shfl_xor(mx, off));
    if ((lane & 31) == 0) maxy2[(size_t)grp * 128 + o] = mx;

    float sv = acc + __shfl_xor(acc, 1);
    sv += __shfl_xor(sv, 2);
    sv += __shfl_xor(sv, 4);
    float q = acc * acc;
    float qv = q + __shfl_xor(q, 1);
    qv += __shfl_xor(qv, 2);
    qv += __shfl_xor(qv, 4);
    if ((lane & 7) == 0) {
      ssum[w][o][lane >> 3] = sv;
      ssq[w][o][lane >> 3] = qv;
    }
  }
  __syncthreads();
  {
    const int o = threadIdx.x & 127;
    const bool isq = threadIdx.x >= 128;
    float s = 0.f;
#pragma unroll
    for (int ww = 0; ww < 4; ++ww)
      for (int k = 0; k < 8; ++k)
        s += isq ? ssq[ww][o][k] : ssum[ww][o][k];
    part2[blockIdx.x * 256 + threadIdx.x] = s;
  }
}

__global__ __launch_bounds__(256)
void final_k(const float* __restrict__ maxy2, const float* __restrict__ AB2,
             float* __restrict__ out) {
  int i = blockIdx.x * 256 + threadIdx.x;
  int o = i & 127;
  out[i] = fmaxf(fmaf(maxy2[i], AB2[o], AB2[128 + o]), 0.f);
}

extern "C" void kernel_launch(void* const* d_in, const int* in_sizes, int n_in,
                              void* d_out, int out_size, void* d_ws, size_t ws_size,
                              hipStream_t stream) {
  const float* data = (const float*)d_in[0];
  const float* feat = (const float*)d_in[1];
  const float* w0 = (const float*)d_in[2];
  const float* b0 = (const float*)d_in[3];
  const float* g0 = (const float*)d_in[4];
  const float* be0 = (const float*)d_in[5];
  const float* w1 = (const float*)d_in[6];
  const float* b1 = (const float*)d_in[7];
  const float* g1 = (const float*)d_in[8];
  const float* be1 = (const float*)d_in[9];
  const float* w2 = (const float*)d_in[10];
  const float* b2 = (const float*)d_in[11];
  const float* g2 = (const float*)d_in[12];
  const float* be2 = (const float*)d_in[13];
  float* out = (float*)d_out;

  float* ws = (float*)d_ws;
  float* cent_ws = ws; ws += (size_t)Bc * Sc * 3;
  float* x0 = ws;      ws += (size_t)6 * Pc;
  float* y1 = ws;      ws += (size_t)64 * Pc;
  float* maxy2 = ws;   ws += (size_t)Bc * Sc * 128;
  float* part0 = ws;   ws += 1024 * 128;
  float* part1 = ws;   ws += 1024 * 128;
  float* part2 = ws;   ws += 1024 * 256;
  float* AB0 = ws;     ws += 128;
  float* AB1 = ws;     ws += 128;
  float* AB2 = ws;     ws += 256;

  fps_kernel<<<Bc, 512, 0, stream>>>(data, out, cent_ws);
  ball_kernel<<<(Bc * Sc) / 4, 256, 0, stream>>>(data, feat, cent_ws, x0);
  pass_a<<<1024, 256, 0, stream>>>(x0, w0, b0, part0);
  reduce_k<<<64, 256, 0, stream>>>(part0, 1024, 64, g0, be0, AB0);
  pass_b<<<Pc / 256, 256, 0, stream>>>(x0, w0, b0, AB0, w1, b1, y1, part1);
  reduce_k<<<64, 256, 0, stream>>>(part1, 1024, 64, g1, be1, AB1);
  pass_c<<<Pc / 256, 256, 0, stream>>>(y1, AB1, w2, b2, maxy2, part2);
  reduce_k<<<128, 256, 0, stream>>>(part2, 1024, 128, g2, be2, AB2);
  final_k<<<(Bc * Sc * 128) / 256, 256, 0, stream>>>(maxy2, AB2, out + (size_t)Bc * Sc * 3);
}

// Round 13
// 816.767 us; speedup vs baseline: 1.1361x; 1.1361x over previous
//
#include <hip/hip_runtime.h>
#include <math.h>

constexpr int Bc = 16;
constexpr int Nc = 8192;
constexpr int Sc = 512;
constexpr int Kc = 32;
constexpr int Pc = Bc * Sc * Kc; // 262144

// DPP-assisted wave64 max stage (ctrl is a compile-time constant)
template <int CTRL>
__device__ __forceinline__ float dpp_max_stage(float x) {
  int p = __builtin_amdgcn_update_dpp(0, __float_as_int(x), CTRL, 0xf, 0xf, true);
  return fmaxf(x, __int_as_float(p));
}

// ---------------------------------------------------------------------------
// FPS (r11-exact, measured 447 us): one block (256 thr = 4 waves) per batch,
// 32 pts/thread. Points mirrored in LDS; no VMEM in the loop. Scalar no-FMA
// distance (bit-exact), strict-> argmax (first-occurrence), DPP wave max +
// ballot index, 4 u64 LDS slots (double-buffered), ONE barrier, 4-read local
// compare, post-barrier lx[sfar] broadcast fetch.
// Measured lessons: 4 waves > 8 waves (barrier lockstep, r12); coords-in-slot
// regressed (r10); pk-asm regressed (r8). Do not revisit.
// ---------------------------------------------------------------------------
__global__ __launch_bounds__(256, 1)
void fps_kernel(const float* __restrict__ data,
                float* __restrict__ cent_out,
                float* __restrict__ cent_ws) {
  const int b = blockIdx.x;
  const int t = threadIdx.x;
  const int lane = t & 63, w = t >> 6;   // w in 0..3

  __shared__ float lx[Nc], ly[Nc], lz[Nc];          // 96 KB point mirror
  __shared__ unsigned long long red_k[2][4];
  __shared__ int idx_hist[Sc];

  const float* db = data + (size_t)b * Nc * 3;

  float px[32], py[32], pz[32], dist[32];
#pragma unroll
  for (int j = 0; j < 32; ++j) {
    int p = t + 256 * j;
    px[j] = db[p * 3 + 0];
    py[j] = db[p * 3 + 1];
    pz[j] = db[p * 3 + 2];
    dist[j] = 1e10f;
    lx[p] = px[j]; ly[p] = py[j]; lz[p] = pz[j];
  }
  __syncthreads();

  int far = 0;
  for (int it = 0; it < Sc; ++it) {
    const int sfar = __builtin_amdgcn_readfirstlane(far);
    if (t == 0) idx_hist[it] = sfar;
    const float cx = lx[sfar];
    const float cy = ly[sfar];
    const float cz = lz[sfar];

    float best = -1.0f; int bj = 0;
#pragma unroll
    for (int j = 0; j < 32; ++j) {
      float dx = __fsub_rn(px[j], cx);
      float dy = __fsub_rn(py[j], cy);
      float dz = __fsub_rn(pz[j], cz);
      float d = __fadd_rn(__fadd_rn(__fmul_rn(dx, dx), __fmul_rn(dy, dy)),
                          __fmul_rn(dz, dz));
      float nd = fminf(dist[j], d);
      dist[j] = nd;
      if (nd > best) { best = nd; bj = j; }  // strict >: first index in lane
    }
    const int bidx = t + 256 * bj;

    // wave max: DPP within row16, shfl across rows
    float wmax = best;
    wmax = dpp_max_stage<0xB1>(wmax);   // quad_perm [1,0,3,2]
    wmax = dpp_max_stage<0x4E>(wmax);   // quad_perm [2,3,0,1]
    wmax = dpp_max_stage<0x141>(wmax);  // row_half_mirror
    wmax = dpp_max_stage<0x140>(wmax);  // row_mirror
    wmax = fmaxf(wmax, __shfl_xor(wmax, 16));
    wmax = fmaxf(wmax, __shfl_xor(wmax, 32));

    // index of first-occurrence achiever
    unsigned long long m = __ballot(best == wmax);
    int idx;
    if (__popcll(m) == 1) {
      idx = __shfl(bidx, (int)__ffsll((long long)m) - 1);
    } else {  // rare exact tie across lanes -> min point index
      int cand = (best == wmax) ? bidx : 0x7fffffff;
#pragma unroll
      for (int off = 32; off; off >>= 1) cand = min(cand, __shfl_xor(cand, off));
      idx = cand;
    }

    unsigned long long key =
        ((unsigned long long)__float_as_uint(wmax) << 32) |
        (unsigned long long)(0xFFFFFFFFu - (unsigned)idx);
    const int par = it & 1;
    if (lane == 0) red_k[par][w] = key;
    __syncthreads();                 // the only barrier; lgkm drain only

    unsigned long long k0 = red_k[par][0];
    unsigned long long k1 = red_k[par][1];
    unsigned long long k2 = red_k[par][2];
    unsigned long long k3 = red_k[par][3];
    unsigned long long ka = (k0 > k1) ? k0 : k1;
    unsigned long long kb = (k2 > k3) ? k2 : k3;
    unsigned long long kk = (ka > kb) ? ka : kb;
    far = (int)(0xFFFFFFFFu - (unsigned)(kk & 0xFFFFFFFFull));
  }

  __syncthreads();
  for (int s = t; s < Sc; s += 256) {
    int id = idx_hist[s];
    float vx = lx[id], vy = ly[id], vz = lz[id];
    size_t o = ((size_t)b * Sc + s) * 3;
    cent_out[o + 0] = vx; cent_out[o + 1] = vy; cent_out[o + 2] = vz;
    cent_ws[o + 0]  = vx; cent_ws[o + 1]  = vy; cent_ws[o + 2]  = vz;
  }
}

// ---------------------------------------------------------------------------
// Ball query + gather + concat (writes x0) FUSED with pass_a (y0 stats).
// The block's 128 x0 points are staged in LDS during the gather, then the
// same block computes its y0 partial sums (fixed-order, deterministic).
// Saves the pass_a dispatch + its x0 global re-read.
// ---------------------------------------------------------------------------
__global__ __launch_bounds__(256)
void ball_kernel(const float* __restrict__ data,
                 const float* __restrict__ feat,
                 const float* __restrict__ cent_ws,
                 const float* __restrict__ w0,
                 const float* __restrict__ b0,
                 float* __restrict__ x0,
                 float* __restrict__ part0) {
  const int w = threadIdx.x >> 6, lane = threadIdx.x & 63;
  const int t = threadIdx.x;
  const int q = blockIdx.x * 4 + w;
  const int b = q >> 9;
  const float* db = data + (size_t)b * Nc * 3;
  const float* fb = feat + (size_t)b * Nc * 3;

  const float qx = cent_ws[q * 3 + 0];
  const float qy = cent_ws[q * 3 + 1];
  const float qz = cent_ws[q * 3 + 2];
  const float q2 = __fadd_rn(__fadd_rn(__fmul_rn(qx, qx), __fmul_rn(qy, qy)),
                             __fmul_rn(qz, qz));

  __shared__ int nbr[4][Kc];
  __shared__ float x0s[6][128];   // block's x0 values, [channel][w*32+k]
  int have = 0;
  for (int base = 0; base < Nc; base += 64) {
    int i = base + lane;
    float px = db[i * 3 + 0], py = db[i * 3 + 1], pz = db[i * 3 + 2];
    float p2 = __fadd_rn(__fadd_rn(__fmul_rn(px, px), __fmul_rn(py, py)),
                         __fmul_rn(pz, pz));
    float dt = fmaf(qz, pz, fmaf(qy, py, __fmul_rn(qx, px)));
    float d = __fadd_rn(__fadd_rn(__fmul_rn(-2.0f, dt), q2), p2);
    bool ok = d <= 0.16f;
    unsigned long long mask = __ballot(ok);
    if (mask) {
      int pos = have + __popcll(mask & ((1ull << lane) - 1ull));
      if (ok && pos < Kc) nbr[w][pos] = i;
      have += __popcll(mask);
      if (have >= Kc) break;
    }
  }
  if (have > Kc) have = Kc;
  __syncthreads();

  if (lane < Kc) {
    int k = lane;
    int j = nbr[w][k < have ? k : 0];
    float sx = __fsub_rn(db[j * 3 + 0], qx);
    float sy = __fsub_rn(db[j * 3 + 1], qy);
    float sz = __fsub_rn(db[j * 3 + 2], qz);
    float fx = fb[j * 3 + 0], fy = fb[j * 3 + 1], fz = fb[j * 3 + 2];
    size_t pidx = (size_t)q * Kc + k;
    x0[(size_t)0 * Pc + pidx] = sx;
    x0[(size_t)1 * Pc + pidx] = sy;
    x0[(size_t)2 * Pc + pidx] = sz;
    x0[(size_t)3 * Pc + pidx] = fx;
    x0[(size_t)4 * Pc + pidx] = fy;
    x0[(size_t)5 * Pc + pidx] = fz;
    int col = w * Kc + k;
    x0s[0][col] = sx; x0s[1][col] = sy; x0s[2][col] = sz;
    x0s[3][col] = fx; x0s[4][col] = fy; x0s[5][col] = fz;
  }
  __syncthreads();

  // y0 stats: thread = (channel o = t&63, point-quarter q4 = t>>6)
  const int o = t & 63, q4 = t >> 6;
  float W[6];
#pragma unroll
  for (int c = 0; c < 6; ++c) W[c] = w0[o * 6 + c];
  const float bias = b0[o];
  float sum = 0.f, sq = 0.f;
#pragma unroll 4
  for (int k = 0; k < 32; ++k) {
    int p = q4 * 32 + k;
    float y = bias;
#pragma unroll
    for (int c = 0; c < 6; ++c) y = fmaf(x0s[c][p], W[c], y);
    sum += y;
    sq = fmaf(y, y, sq);
  }
  __shared__ float bsum[4][64], bsq[4][64];
  bsum[q4][o] = sum; bsq[q4][o] = sq;
  __syncthreads();
  if (t < 64)
    part0[blockIdx.x * 128 + t] =
        ((bsum[0][t] + bsum[1][t]) + bsum[2][t]) + bsum[3][t];
  else if (t < 128) {
    int oo = t - 64;
    part0[blockIdx.x * 128 + t] =
        ((bsq[0][oo] + bsq[1][oo]) + bsq[2][oo]) + bsq[3][oo];
  }
}

// One block per channel; 256-thread fixed-order tree (deterministic, double).
__global__ __launch_bounds__(256)
void reduce_k(const float* __restrict__ part, int nblk, int nch,
              const float* __restrict__ g, const float* __restrict__ be,
              float* __restrict__ AB) {
  const int o = blockIdx.x;
  const int t = threadIdx.x;
  double sum = 0.0, sq = 0.0;
  for (int i = t; i < nblk; i += 256) {
    sum += (double)part[(size_t)i * (2 * nch) + o];
    sq  += (double)part[(size_t)i * (2 * nch) + nch + o];
  }
  __shared__ double ls[256], lq[256];
  ls[t] = sum; lq[t] = sq;
  __syncthreads();
  for (int s = 128; s > 0; s >>= 1) {
    if (t < s) { ls[t] += ls[t + s]; lq[t] += lq[t + s]; }
    __syncthreads();
  }
  if (t == 0) {
    double m = ls[0] / (double)Pc;
    double v = lq[0] / (double)Pc - m * m;
    double A = (double)g[o] / sqrt(v + 1e-5);
    AB[o] = (float)A;
    AB[nch + o] = (float)((double)be[o] - m * A);
  }
}

// reduce for layer 2 FUSED with the final affine+relu epilogue: block o
// computes A2[o],B2[o] then applies them to all 8192 pooled groups.
__global__ __launch_bounds__(256)
void reduce2_final_k(const float* __restrict__ part, int nblk,
                     const float* __restrict__ g, const float* __restrict__ be,
                     const float* __restrict__ maxy2,
                     float* __restrict__ out) {
  const int o = blockIdx.x;          // 0..127
  const int t = threadIdx.x;
  double sum = 0.0, sq = 0.0;
  for (int i = t; i < nblk; i += 256) {
    sum += (double)part[(size_t)i * 256 + o];
    sq  += (double)part[(size_t)i * 256 + 128 + o];
  }
  __shared__ double ls[256], lq[256];
  ls[t] = sum; lq[t] = sq;
  __syncthreads();
  for (int s = 128; s > 0; s >>= 1) {
    if (t < s) { ls[t] += ls[t + s]; lq[t] += lq[t + s]; }
    __syncthreads();
  }
  __shared__ float sA, sB;
  if (t == 0) {
    double m = ls[0] / (double)Pc;
    double v = lq[0] / (double)Pc - m * m;
    double A = (double)g[o] / sqrt(v + 1e-5);
    sA = (float)A;
    sB = (float)((double)be[o] - m * A);
  }
  __syncthreads();
  const float A = sA, B = sB;
  for (int grp = t; grp < Bc * Sc; grp += 256) {
    float v = maxy2[(size_t)grp * 128 + o];
    out[(size_t)grp * 128 + o] = fmaxf(fmaf(v, A, B), 0.f);
  }
}

// Stats: 2-level lane shuffle (groups of 4) + padded LDS slab, block epilogue.
__global__ __launch_bounds__(256)
void pass_b(const float* __restrict__ x0, const float* __restrict__ w0,
            const float* __restrict__ b0, const float* __restrict__ AB0,
            const float* __restrict__ w1, const float* __restrict__ b1,
            float* __restrict__ y1, float* __restrict__ part1) {
  const int p = blockIdx.x * 256 + threadIdx.x;
  const int lane = threadIdx.x & 63, w = threadIdx.x >> 6;

  float xin[6];
#pragma unroll
  for (int c = 0; c < 6; ++c) xin[c] = x0[(size_t)c * Pc + p];

  float x1[64];
#pragma unroll
  for (int o = 0; o < 64; ++o) {
    float y = b0[o];
#pragma unroll
    for (int c = 0; c < 6; ++c) y = fmaf(xin[c], w0[o * 6 + c], y);
    x1[o] = fmaxf(fmaf(y, AB0[o], AB0[64 + o]), 0.f);
  }

  __shared__ float ssum[4][64][17], ssq[4][64][17];  // padded: stride 17

  for (int o = 0; o < 64; ++o) {
    float a0 = b1[o], a1 = 0.f, a2 = 0.f, a3 = 0.f;
#pragma unroll
    for (int c = 0; c < 64; c += 4) {
      a0 = fmaf(x1[c + 0], w1[o * 64 + c + 0], a0);
      a1 = fmaf(x1[c + 1], w1[o * 64 + c + 1], a1);
      a2 = fmaf(x1[c + 2], w1[o * 64 + c + 2], a2);
      a3 = fmaf(x1[c + 3], w1[o * 64 + c + 3], a3);
    }
    float acc = (a0 + a1) + (a2 + a3);
    y1[(size_t)o * Pc + p] = acc;

    float sv = acc + __shfl_xor(acc, 1);
    sv += __shfl_xor(sv, 2);
    float q = acc * acc;
    float qv = q + __shfl_xor(q, 1);
    qv += __shfl_xor(qv, 2);
    if ((lane & 3) == 0) {
      ssum[w][o][lane >> 2] = sv;
      ssq[w][o][lane >> 2] = qv;
    }
  }
  __syncthreads();
  if (threadIdx.x < 128) {
    const int o = threadIdx.x & 63;
    const bool isq = threadIdx.x >= 64;
    float s = 0.f;
#pragma unroll
    for (int ww = 0; ww < 4; ++ww)
      for (int k = 0; k < 16; ++k)
        s += isq ? ssq[ww][o][k] : ssum[ww][o][k];
    part1[blockIdx.x * 128 + threadIdx.x] = s;
  }
}

// Stats: 3-level lane shuffle (groups of 8) + padded LDS slab, block epilogue.
__global__ __launch_bounds__(256)
void pass_c(const float* __restrict__ y1, const float* __restrict__ AB1,
            const float* __restrict__ w2, const float* __restrict__ b2,
            float* __restrict__ maxy2, float* __restrict__ part2) {
  const int p = blockIdx.x * 256 + threadIdx.x;
  const int lane = threadIdx.x & 63, w = threadIdx.x >> 6;
  const int grp = p >> 5;

  float x2[64];
#pragma unroll
  for (int c = 0; c < 64; ++c) {
    float v = y1[(size_t)c * Pc + p];
    x2[c] = fmaxf(fmaf(v, AB1[c], AB1[64 + c]), 0.f);
  }

  __shared__ float ssum[4][128][9], ssq[4][128][9];  // padded: stride 9

  for (int o = 0; o < 128; ++o) {
    float a0 = b2[o], a1 = 0.f, a2 = 0.f, a3 = 0.f;
#pragma unroll
    for (int c = 0; c < 64; c += 4) {
      a0 = fmaf(x2[c + 0], w2[o * 64 + c + 0], a0);
      a1 = fmaf(x2[c + 1], w2[o * 64 + c + 1], a1);
      a2 = fmaf(x2[c + 2], w2[o * 64 + c + 2], a2);
      a3 = fmaf(x2[c + 3], w2[o * 64 + c + 3], a3);
    }
    float acc = (a0 + a1) + (a2 + a3);

    float mx = acc;
#pragma unroll
    for (int off = 16; off > 0; off >>= 1) mx = fmaxf(mx, __shfl_xor(mx, off));
    if ((lane & 31) == 0) maxy2[(size_t)grp * 128 + o] = mx;

    float sv = acc + __shfl_xor(acc, 1);
    sv += __shfl_xor(sv, 2);
    sv += __shfl_xor(sv, 4);
    float q = acc * acc;
    float qv = q + __shfl_xor(q, 1);
    qv += __shfl_xor(qv, 2);
    qv += __shfl_xor(qv, 4);
    if ((lane & 7) == 0) {
      ssum[w][o][lane >> 3] = sv;
      ssq[w][o][lane >> 3] = qv;
    }
  }
  __syncthreads();
  {
    const int o = threadIdx.x & 127;
    const bool isq = threadIdx.x >= 128;
    float s = 0.f;
#pragma unroll
    for (int ww = 0; ww < 4; ++ww)
      for (int k = 0; k < 8; ++k)
        s += isq ? ssq[ww][o][k] : ssum[ww][o][k];
    part2[blockIdx.x * 256 + threadIdx.x] = s;
  }
}

extern "C" void kernel_launch(void* const* d_in, const int* in_sizes, int n_in,
                              void* d_out, int out_size, void* d_ws, size_t ws_size,
                              hipStream_t stream) {
  const float* data = (const float*)d_in[0];
  const float* feat = (const float*)d_in[1];
  const float* w0 = (const float*)d_in[2];
  const float* b0 = (const float*)d_in[3];
  const float* g0 = (const float*)d_in[4];
  const float* be0 = (const float*)d_in[5];
  const float* w1 = (const float*)d_in[6];
  const float* b1 = (const float*)d_in[7];
  const float* g1 = (const float*)d_in[8];
  const float* be1 = (const float*)d_in[9];
  const float* w2 = (const float*)d_in[10];
  const float* b2 = (const float*)d_in[11];
  const float* g2 = (const float*)d_in[12];
  const float* be2 = (const float*)d_in[13];
  float* out = (float*)d_out;

  float* ws = (float*)d_ws;
  float* cent_ws = ws; ws += (size_t)Bc * Sc * 3;
  float* x0 = ws;      ws += (size_t)6 * Pc;
  float* y1 = ws;      ws += (size_t)64 * Pc;
  float* maxy2 = ws;   ws += (size_t)Bc * Sc * 128;
  float* part0 = ws;   ws += 2048 * 128;
  float* part1 = ws;   ws += 1024 * 128;
  float* part2 = ws;   ws += 1024 * 256;
  float* AB0 = ws;     ws += 128;
  float* AB1 = ws;     ws += 128;

  fps_kernel<<<Bc, 256, 0, stream>>>(data, out, cent_ws);
  ball_kernel<<<(Bc * Sc) / 4, 256, 0, stream>>>(data, feat, cent_ws,
                                                 w0, b0, x0, part0);
  reduce_k<<<64, 256, 0, stream>>>(part0, 2048, 64, g0, be0, AB0);
  pass_b<<<Pc / 256, 256, 0, stream>>>(x0, w0, b0, AB0, w1, b1, y1, part1);
  reduce_k<<<64, 256, 0, stream>>>(part1, 1024, 64, g1, be1, AB1);
  pass_c<<<Pc / 256, 256, 0, stream>>>(y1, AB1, w2, b2, maxy2, part2);
  reduce2_final_k<<<128, 256, 0, stream>>>(part2, 1024, g2, be2, maxy2,
                                           out + (size_t)Bc * Sc * 3);
}

// Round 14
// 808.658 us; speedup vs baseline: 1.1474x; 1.0100x over previous
//
#include <hip/hip_runtime.h>
#include <math.h>

constexpr int Bc = 16;
constexpr int Nc = 8192;
constexpr int Sc = 512;
constexpr int Kc = 32;
constexpr int Pc = Bc * Sc * Kc; // 262144

typedef float v2f __attribute__((ext_vector_type(2)));

#if defined(__has_builtin)
#if __has_builtin(__builtin_elementwise_fma)
#define PKFMA(a, b, c) __builtin_elementwise_fma(a, b, c)
#endif
#endif
#ifndef PKFMA
__device__ __forceinline__ v2f pkfma_(v2f a, v2f b, v2f c) {
  v2f r; r.x = fmaf(a.x, b.x, c.x); r.y = fmaf(a.y, b.y, c.y); return r;
}
#define PKFMA(a, b, c) pkfma_(a, b, c)
#endif

// DPP-assisted wave64 max stage (ctrl is a compile-time constant)
template <int CTRL>
__device__ __forceinline__ float dpp_max_stage(float x) {
  int p = __builtin_amdgcn_update_dpp(0, __float_as_int(x), CTRL, 0xf, 0xf, true);
  return fmaxf(x, __int_as_float(p));
}

// ---------------------------------------------------------------------------
// FPS (r11-exact, measured 447 us). Measured lessons: 4 waves > 8 waves
// (barrier lockstep, r12); coords-in-slot regressed (r10); pk-asm in the
// distance loop regressed (r8). Do not revisit.
// ---------------------------------------------------------------------------
__global__ __launch_bounds__(256, 1)
void fps_kernel(const float* __restrict__ data,
                float* __restrict__ cent_out,
                float* __restrict__ cent_ws) {
  const int b = blockIdx.x;
  const int t = threadIdx.x;
  const int lane = t & 63, w = t >> 6;   // w in 0..3

  __shared__ float lx[Nc], ly[Nc], lz[Nc];          // 96 KB point mirror
  __shared__ unsigned long long red_k[2][4];
  __shared__ int idx_hist[Sc];

  const float* db = data + (size_t)b * Nc * 3;

  float px[32], py[32], pz[32], dist[32];
#pragma unroll
  for (int j = 0; j < 32; ++j) {
    int p = t + 256 * j;
    px[j] = db[p * 3 + 0];
    py[j] = db[p * 3 + 1];
    pz[j] = db[p * 3 + 2];
    dist[j] = 1e10f;
    lx[p] = px[j]; ly[p] = py[j]; lz[p] = pz[j];
  }
  __syncthreads();

  int far = 0;
  for (int it = 0; it < Sc; ++it) {
    const int sfar = __builtin_amdgcn_readfirstlane(far);
    if (t == 0) idx_hist[it] = sfar;
    const float cx = lx[sfar];
    const float cy = ly[sfar];
    const float cz = lz[sfar];

    float best = -1.0f; int bj = 0;
#pragma unroll
    for (int j = 0; j < 32; ++j) {
      float dx = __fsub_rn(px[j], cx);
      float dy = __fsub_rn(py[j], cy);
      float dz = __fsub_rn(pz[j], cz);
      float d = __fadd_rn(__fadd_rn(__fmul_rn(dx, dx), __fmul_rn(dy, dy)),
                          __fmul_rn(dz, dz));
      float nd = fminf(dist[j], d);
      dist[j] = nd;
      if (nd > best) { best = nd; bj = j; }  // strict >: first index in lane
    }
    const int bidx = t + 256 * bj;

    float wmax = best;
    wmax = dpp_max_stage<0xB1>(wmax);   // quad_perm [1,0,3,2]
    wmax = dpp_max_stage<0x4E>(wmax);   // quad_perm [2,3,0,1]
    wmax = dpp_max_stage<0x141>(wmax);  // row_half_mirror
    wmax = dpp_max_stage<0x140>(wmax);  // row_mirror
    wmax = fmaxf(wmax, __shfl_xor(wmax, 16));
    wmax = fmaxf(wmax, __shfl_xor(wmax, 32));

    unsigned long long m = __ballot(best == wmax);
    int idx;
    if (__popcll(m) == 1) {
      idx = __shfl(bidx, (int)__ffsll((long long)m) - 1);
    } else {
      int cand = (best == wmax) ? bidx : 0x7fffffff;
#pragma unroll
      for (int off = 32; off; off >>= 1) cand = min(cand, __shfl_xor(cand, off));
      idx = cand;
    }

    unsigned long long key =
        ((unsigned long long)__float_as_uint(wmax) << 32) |
        (unsigned long long)(0xFFFFFFFFu - (unsigned)idx);
    const int par = it & 1;
    if (lane == 0) red_k[par][w] = key;
    __syncthreads();                 // the only barrier; lgkm drain only

    unsigned long long k0 = red_k[par][0];
    unsigned long long k1 = red_k[par][1];
    unsigned long long k2 = red_k[par][2];
    unsigned long long k3 = red_k[par][3];
    unsigned long long ka = (k0 > k1) ? k0 : k1;
    unsigned long long kb = (k2 > k3) ? k2 : k3;
    unsigned long long kk = (ka > kb) ? ka : kb;
    far = (int)(0xFFFFFFFFu - (unsigned)(kk & 0xFFFFFFFFull));
  }

  __syncthreads();
  for (int s = t; s < Sc; s += 256) {
    int id = idx_hist[s];
    float vx = lx[id], vy = ly[id], vz = lz[id];
    size_t o = ((size_t)b * Sc + s) * 3;
    cent_out[o + 0] = vx; cent_out[o + 1] = vy; cent_out[o + 2] = vz;
    cent_ws[o + 0]  = vx; cent_ws[o + 1]  = vy; cent_ws[o + 2]  = vz;
  }
}

// ---------------------------------------------------------------------------
// Ball query + gather + concat (writes x0) fused with y0 stats (r13).
// ---------------------------------------------------------------------------
__global__ __launch_bounds__(256)
void ball_kernel(const float* __restrict__ data,
                 const float* __restrict__ feat,
                 const float* __restrict__ cent_ws,
                 const float* __restrict__ w0,
                 const float* __restrict__ b0,
                 float* __restrict__ x0,
                 float* __restrict__ part0) {
  const int w = threadIdx.x >> 6, lane = threadIdx.x & 63;
  const int t = threadIdx.x;
  const int q = blockIdx.x * 4 + w;
  const int b = q >> 9;
  const float* db = data + (size_t)b * Nc * 3;
  const float* fb = feat + (size_t)b * Nc * 3;

  const float qx = cent_ws[q * 3 + 0];
  const float qy = cent_ws[q * 3 + 1];
  const float qz = cent_ws[q * 3 + 2];
  const float q2 = __fadd_rn(__fadd_rn(__fmul_rn(qx, qx), __fmul_rn(qy, qy)),
                             __fmul_rn(qz, qz));

  __shared__ int nbr[4][Kc];
  __shared__ float x0s[6][128];
  int have = 0;
  for (int base = 0; base < Nc; base += 64) {
    int i = base + lane;
    float px = db[i * 3 + 0], py = db[i * 3 + 1], pz = db[i * 3 + 2];
    float p2 = __fadd_rn(__fadd_rn(__fmul_rn(px, px), __fmul_rn(py, py)),
                         __fmul_rn(pz, pz));
    float dt = fmaf(qz, pz, fmaf(qy, py, __fmul_rn(qx, px)));
    float d = __fadd_rn(__fadd_rn(__fmul_rn(-2.0f, dt), q2), p2);
    bool ok = d <= 0.16f;
    unsigned long long mask = __ballot(ok);
    if (mask) {
      int pos = have + __popcll(mask & ((1ull << lane) - 1ull));
      if (ok && pos < Kc) nbr[w][pos] = i;
      have += __popcll(mask);
      if (have >= Kc) break;
    }
  }
  if (have > Kc) have = Kc;
  __syncthreads();

  if (lane < Kc) {
    int k = lane;
    int j = nbr[w][k < have ? k : 0];
    float sx = __fsub_rn(db[j * 3 + 0], qx);
    float sy = __fsub_rn(db[j * 3 + 1], qy);
    float sz = __fsub_rn(db[j * 3 + 2], qz);
    float fx = fb[j * 3 + 0], fy = fb[j * 3 + 1], fz = fb[j * 3 + 2];
    size_t pidx = (size_t)q * Kc + k;
    x0[(size_t)0 * Pc + pidx] = sx;
    x0[(size_t)1 * Pc + pidx] = sy;
    x0[(size_t)2 * Pc + pidx] = sz;
    x0[(size_t)3 * Pc + pidx] = fx;
    x0[(size_t)4 * Pc + pidx] = fy;
    x0[(size_t)5 * Pc + pidx] = fz;
    int col = w * Kc + k;
    x0s[0][col] = sx; x0s[1][col] = sy; x0s[2][col] = sz;
    x0s[3][col] = fx; x0s[4][col] = fy; x0s[5][col] = fz;
  }
  __syncthreads();

  const int o = t & 63, q4 = t >> 6;
  float W[6];
#pragma unroll
  for (int c = 0; c < 6; ++c) W[c] = w0[o * 6 + c];
  const float bias = b0[o];
  float sum = 0.f, sq = 0.f;
#pragma unroll 4
  for (int k = 0; k < 32; ++k) {
    int p = q4 * 32 + k;
    float y = bias;
#pragma unroll
    for (int c = 0; c < 6; ++c) y = fmaf(x0s[c][p], W[c], y);
    sum += y;
    sq = fmaf(y, y, sq);
  }
  __shared__ float bsum[4][64], bsq[4][64];
  bsum[q4][o] = sum; bsq[q4][o] = sq;
  __syncthreads();
  if (t < 64)
    part0[blockIdx.x * 128 + t] =
        ((bsum[0][t] + bsum[1][t]) + bsum[2][t]) + bsum[3][t];
  else if (t < 128) {
    int oo = t - 64;
    part0[blockIdx.x * 128 + t] =
        ((bsq[0][oo] + bsq[1][oo]) + bsq[2][oo]) + bsq[3][oo];
  }
}

// One block per channel; 256-thread fixed-order tree (deterministic, double).
__global__ __launch_bounds__(256)
void reduce_k(const float* __restrict__ part, int nblk, int nch,
              const float* __restrict__ g, const float* __restrict__ be,
              float* __restrict__ AB) {
  const int o = blockIdx.x;
  const int t = threadIdx.x;
  double sum = 0.0, sq = 0.0;
  for (int i = t; i < nblk; i += 256) {
    sum += (double)part[(size_t)i * (2 * nch) + o];
    sq  += (double)part[(size_t)i * (2 * nch) + nch + o];
  }
  __shared__ double ls[256], lq[256];
  ls[t] = sum; lq[t] = sq;
  __syncthreads();
  for (int s = 128; s > 0; s >>= 1) {
    if (t < s) { ls[t] += ls[t + s]; lq[t] += lq[t + s]; }
    __syncthreads();
  }
  if (t == 0) {
    double m = ls[0] / (double)Pc;
    double v = lq[0] / (double)Pc - m * m;
    double A = (double)g[o] / sqrt(v + 1e-5);
    AB[o] = (float)A;
    AB[nch + o] = (float)((double)be[o] - m * A);
  }
}

// reduce layer-2 stats fused with the final affine+relu epilogue.
__global__ __launch_bounds__(256)
void reduce2_final_k(const float* __restrict__ part, int nblk,
                     const float* __restrict__ g, const float* __restrict__ be,
                     const float* __restrict__ maxy2,
                     float* __restrict__ out) {
  const int o = blockIdx.x;          // 0..127
  const int t = threadIdx.x;
  double sum = 0.0, sq = 0.0;
  for (int i = t; i < nblk; i += 256) {
    sum += (double)part[(size_t)i * 256 + o];
    sq  += (double)part[(size_t)i * 256 + 128 + o];
  }
  __shared__ double ls[256], lq[256];
  ls[t] = sum; lq[t] = sq;
  __syncthreads();
  for (int s = 128; s > 0; s >>= 1) {
    if (t < s) { ls[t] += ls[t + s]; lq[t] += lq[t + s]; }
    __syncthreads();
  }
  __shared__ float sA, sB;
  if (t == 0) {
    double m = ls[0] / (double)Pc;
    double v = lq[0] / (double)Pc - m * m;
    double A = (double)g[o] / sqrt(v + 1e-5);
    sA = (float)A;
    sB = (float)((double)be[o] - m * A);
  }
  __syncthreads();
  const float A = sA, B = sB;
  for (int grp = t; grp < Bc * Sc; grp += 256) {
    float v = maxy2[(size_t)grp * 128 + o];
    out[(size_t)grp * 128 + o] = fmaxf(fmaf(v, A, B), 0.f);
  }
}

// pass_b: conv1 via v_pk_fma_f32 (2 MACs/inst, bit-identical to the 4-acc
// split: a01=(c%4==0,1), a23=(c%4==2,3), same final combine).
__global__ __launch_bounds__(256)
void pass_b(const float* __restrict__ x0, const float* __restrict__ w0,
            const float* __restrict__ b0, const float* __restrict__ AB0,
            const float* __restrict__ w1, const float* __restrict__ b1,
            float* __restrict__ y1, float* __restrict__ part1) {
  const int p = blockIdx.x * 256 + threadIdx.x;
  const int lane = threadIdx.x & 63, w = threadIdx.x >> 6;

  float xin[6];
#pragma unroll
  for (int c = 0; c < 6; ++c) xin[c] = x0[(size_t)c * Pc + p];

  float x1s[64];
#pragma unroll
  for (int o = 0; o < 64; ++o) {
    float y = b0[o];
#pragma unroll
    for (int c = 0; c < 6; ++c) y = fmaf(xin[c], w0[o * 6 + c], y);
    x1s[o] = fmaxf(fmaf(y, AB0[o], AB0[64 + o]), 0.f);
  }
  v2f x1p[32];
#pragma unroll
  for (int j = 0; j < 32; ++j) { x1p[j].x = x1s[2 * j]; x1p[j].y = x1s[2 * j + 1]; }

  const v2f* __restrict__ w1v = (const v2f*)w1;

  __shared__ float ssum[4][64][17], ssq[4][64][17];  // padded: stride 17

  for (int o = 0; o < 64; ++o) {
    v2f a01; a01.x = b1[o]; a01.y = 0.f;
    v2f a23; a23.x = 0.f;   a23.y = 0.f;
#pragma unroll
    for (int c2 = 0; c2 < 32; c2 += 2) {
      a01 = PKFMA(x1p[c2 + 0], w1v[o * 32 + c2 + 0], a01);
      a23 = PKFMA(x1p[c2 + 1], w1v[o * 32 + c2 + 1], a23);
    }
    float acc = (a01.x + a01.y) + (a23.x + a23.y);
    y1[(size_t)o * Pc + p] = acc;

    float sv = acc + __shfl_xor(acc, 1);
    sv += __shfl_xor(sv, 2);
    float q = acc * acc;
    float qv = q + __shfl_xor(q, 1);
    qv += __shfl_xor(qv, 2);
    if ((lane & 3) == 0) {
      ssum[w][o][lane >> 2] = sv;
      ssq[w][o][lane >> 2] = qv;
    }
  }
  __syncthreads();
  if (threadIdx.x < 128) {
    const int o = threadIdx.x & 63;
    const bool isq = threadIdx.x >= 64;
    float s = 0.f;
#pragma unroll
    for (int ww = 0; ww < 4; ++ww)
      for (int k = 0; k < 16; ++k)
        s += isq ? ssq[ww][o][k] : ssum[ww][o][k];
    part1[blockIdx.x * 128 + threadIdx.x] = s;
  }
}

// pass_c: conv2 via v_pk_fma_f32 (same bit-identical 4-acc mapping).
__global__ __launch_bounds__(256)
void pass_c(const float* __restrict__ y1, const float* __restrict__ AB1,
            const float* __restrict__ w2, const float* __restrict__ b2,
            float* __restrict__ maxy2, float* __restrict__ part2) {
  const int p = blockIdx.x * 256 + threadIdx.x;
  const int lane = threadIdx.x & 63, w = threadIdx.x >> 6;
  const int grp = p >> 5;

  v2f x2p[32];
#pragma unroll
  for (int c = 0; c < 64; c += 2) {
    float v0 = y1[(size_t)c * Pc + p];
    float v1 = y1[(size_t)(c + 1) * Pc + p];
    x2p[c >> 1].x = fmaxf(fmaf(v0, AB1[c], AB1[64 + c]), 0.f);
    x2p[c >> 1].y = fmaxf(fmaf(v1, AB1[c + 1], AB1[64 + c + 1]), 0.f);
  }

  const v2f* __restrict__ w2v = (const v2f*)w2;

  __shared__ float ssum[4][128][9], ssq[4][128][9];  // padded: stride 9

  for (int o = 0; o < 128; ++o) {
    v2f a01; a01.x = b2[o]; a01.y = 0.f;
    v2f a23; a23.x = 0.f;   a23.y = 0.f;
#pragma unroll
    for (int c2 = 0; c2 < 32; c2 += 2) {
      a01 = PKFMA(x2p[c2 + 0], w2v[o * 32 + c2 + 0], a01);
      a23 = PKFMA(x2p[c2 + 1], w2v[o * 32 + c2 + 1], a23);
    }
    float acc = (a01.x + a01.y) + (a23.x + a23.y);

    float mx = acc;
#pragma unroll
    for (int off = 16; off > 0; off >>= 1) mx = fmaxf(mx, __shfl_xor(mx, off));
    if ((lane & 31) == 0) maxy2[(size_t)grp * 128 + o] = mx;

    float sv = acc + __shfl_xor(acc, 1);
    sv += __shfl_xor(sv, 2);
    sv += __shfl_xor(sv, 4);
    float q = acc * acc;
    float qv = q + __shfl_xor(q, 1);
    qv += __shfl_xor(qv, 2);
    qv += __shfl_xor(qv, 4);
    if ((lane & 7) == 0) {
      ssum[w][o][lane >> 3] = sv;
      ssq[w][o][lane >> 3] = qv;
    }
  }
  __syncthreads();
  {
    const int o = threadIdx.x & 127;
    const bool isq = threadIdx.x >= 128;
    float s = 0.f;
#pragma unroll
    for (int ww = 0; ww < 4; ++ww)
      for (int k = 0; k < 8; ++k)
        s += isq ? ssq[ww][o][k] : ssum[ww][o][k];
    part2[blockIdx.x * 256 + threadIdx.x] = s;
  }
}

extern "C" void kernel_launch(void* const* d_in, const int* in_sizes, int n_in,
                              void* d_out, int out_size, void* d_ws, size_t ws_size,
                              hipStream_t stream) {
  const float* data = (const float*)d_in[0];
  const float* feat = (const float*)d_in[1];
  const float* w0 = (const float*)d_in[2];
  const float* b0 = (const float*)d_in[3];
  const float* g0 = (const float*)d_in[4];
  const float* be0 = (const float*)d_in[5];
  const float* w1 = (const float*)d_in[6];
  const float* b1 = (const float*)d_in[7];
  const float* g1 = (const float*)d_in[8];
  const float* be1 = (const float*)d_in[9];
  const float* w2 = (const float*)d_in[10];
  const float* b2 = (const float*)d_in[11];
  const float* g2 = (const float*)d_in[12];
  const float* be2 = (const float*)d_in[13];
  float* out = (float*)d_out;

  float* ws = (float*)d_ws;
  float* cent_ws = ws; ws += (size_t)Bc * Sc * 3;
  float* x0 = ws;      ws += (size_t)6 * Pc;
  float* y1 = ws;      ws += (size_t)64 * Pc;
  float* maxy2 = ws;   ws += (size_t)Bc * Sc * 128;
  float* part0 = ws;   ws += 2048 * 128;
  float* part1 = ws;   ws += 1024 * 128;
  float* part2 = ws;   ws += 1024 * 256;
  float* AB0 = ws;     ws += 128;
  float* AB1 = ws;     ws += 128;

  fps_kernel<<<Bc, 256, 0, stream>>>(data, out, cent_ws);
  ball_kernel<<<(Bc * Sc) / 4, 256, 0, stream>>>(data, feat, cent_ws,
                                                 w0, b0, x0, part0);
  reduce_k<<<64, 256, 0, stream>>>(part0, 2048, 64, g0, be0, AB0);
  pass_b<<<Pc / 256, 256, 0, stream>>>(x0, w0, b0, AB0, w1, b1, y1, part1);
  reduce_k<<<64, 256, 0, stream>>>(part1, 1024, 64, g1, be1, AB1);
  pass_c<<<Pc / 256, 256, 0, stream>>>(y1, AB1, w2, b2, maxy2, part2);
  reduce2_final_k<<<128, 256, 0, stream>>>(part2, 1024, g2, be2, maxy2,
                                           out + (size_t)Bc * Sc * 3);
}